// Round 1
// baseline (217.866 us; speedup 1.0000x reference)
//
#include <hip/hip_runtime.h>

#define B_   64
#define H_   448
#define W_   448
#define OUT_ 256
#define HB_  486
#define WB_  486
#define HW_  (H_*W_)
#define OO_  (OUT_*OUT_)

__device__ __forceinline__ float clip01(float v) { return fminf(fmaxf(v, 0.f), 1.f); }
__device__ __forceinline__ float pmodf_(float a, float m) {
  float r = fmodf(a, m);
  return (r < 0.f) ? r + m : r;
}

// ---------------- bbox init ----------------
__global__ void k_init(int* __restrict__ bbox) {
  int b = threadIdx.x;
  if (b < B_) {
    bbox[b*4+0] = W_;   // minx
    bbox[b*4+1] = -1;   // maxx
    bbox[b*4+2] = H_;   // miny
    bbox[b*4+3] = -1;   // maxy
  }
}

// ---------------- mask + bbox ----------------
__global__ void k_bbox(const float* __restrict__ wc, unsigned char* __restrict__ maskb,
                       int* __restrict__ bbox, int useMask) {
  int blk = blockIdx.x;
  int b = blk >> 6;            // 64 chunks per sample
  int chunk = blk & 63;
  const int CHUNK = HW_ / 64;  // 3136
  int base = chunk * CHUNK;
  const float* w0 = wc + (size_t)b*3*HW_;
  const float* w1 = w0 + HW_;
  const float* w2 = w1 + HW_;
  int tid = threadIdx.x;
  int mnY = H_, mxY = -1, mnX = W_, mxX = -1;
  for (int j = tid; j < CHUNK; j += 256) {
    int i = base + j;
    bool m = (w0[i] != 0.f) && (w1[i] != 0.f) && (w2[i] != 0.f);
    if (useMask) maskb[(size_t)b*HW_ + i] = (unsigned char)m;
    if (m) {
      int y = i / W_, x = i - y*W_;
      mnY = min(mnY, y); mxY = max(mxY, y);
      mnX = min(mnX, x); mxX = max(mxX, x);
    }
  }
  __shared__ int s0[256], s1[256], s2[256], s3[256];
  s0[tid]=mnY; s1[tid]=mxY; s2[tid]=mnX; s3[tid]=mxX;
  __syncthreads();
  for (int off = 128; off > 0; off >>= 1) {
    if (tid < off) {
      s0[tid] = min(s0[tid], s0[tid+off]);
      s1[tid] = max(s1[tid], s1[tid+off]);
      s2[tid] = min(s2[tid], s2[tid+off]);
      s3[tid] = max(s3[tid], s3[tid+off]);
    }
    __syncthreads();
  }
  if (tid == 0) {
    atomicMin(&bbox[b*4+2], s0[0]);
    atomicMax(&bbox[b*4+3], s1[0]);
    atomicMin(&bbox[b*4+0], s2[0]);
    atomicMax(&bbox[b*4+1], s3[0]);
  }
}

// ---------------- composite + brightness + gray partial sums ----------------
__global__ void k_compose(const float* __restrict__ img, const float* __restrict__ bg,
                          const float* __restrict__ wc, const unsigned char* __restrict__ maskb,
                          const float* __restrict__ col, const float* __restrict__ bri,
                          const int* __restrict__ cbuf, const int* __restrict__ bbox,
                          float* __restrict__ xout, float* __restrict__ partial, int useMask) {
  int tid = threadIdx.x;
  int blk = blockIdx.x;
  int b = blk >> 8;                 // 256 blocks per sample
  int p = ((blk & 255) << 8) | tid; // pixel in [0, 65536)
  int py = p >> 8, px = p & 255;

  int minx = bbox[b*4+0], maxx = bbox[b*4+1], miny = bbox[b*4+2], maxy = bbox[b*4+3];
  if (maxy < 0) { miny = 0; maxy = H_-1; }
  if (maxx < 0) { minx = 0; maxx = W_-1; }
  int c0 = cbuf[b*5+0], c1 = cbuf[b*5+1], c2 = cbuf[b*5+2], c3 = cbuf[b*5+3], c4 = cbuf[b*5+4];
  int Hp = maxy - miny + 1 + c2 + c3;
  int Wp = maxx - minx + 1 + c0 + c1;
  bool usebg = (c4 > 2);
  float colr = col[b*3+0], colg = col[b*3+1], colb = col[b*3+2];

  // src_coords (exactly as reference: w computed before clamping i0)
  float sy = (py + 0.5f) * ((float)Hp / (float)OUT_) - 0.5f;
  sy = fmaxf(sy, 0.f);
  int y0 = (int)floorf(sy);
  float wy = sy - (float)y0;
  y0 = min(y0, Hp-1);
  int y1 = min(y0+1, Hp-1);
  float sx = (px + 0.5f) * ((float)Wp / (float)OUT_) - 0.5f;
  sx = fmaxf(sx, 0.f);
  int x0 = (int)floorf(sx);
  float wx = sx - (float)x0;
  x0 = min(x0, Wp-1);
  int x1 = min(x0+1, Wp-1);

  const float* imgb = img + (size_t)b*3*HW_;
  const float* bgb  = bg  + (size_t)b*3*HB_*WB_;
  const float* w0p  = wc  + (size_t)b*3*HW_;
  const unsigned char* mb = maskb + (size_t)b*HW_;

  float a00[3], a01[3], a10[3], a11[3];
  auto comp = [&](int cy, int cx, float* o) {
    int oy = cy - c2 + miny;
    int ox = cx - c0 + minx;
    bool valid = (oy >= miny) && (oy <= maxy) && (ox >= minx) && (ox <= maxx);
    float mval = 0.f;
    if (valid) {
      int mi = oy * W_ + ox;
      if (useMask) mval = (float)mb[mi];
      else mval = (w0p[mi] != 0.f && w0p[mi+HW_] != 0.f && w0p[mi+2*HW_] != 0.f) ? 1.f : 0.f;
    }
    float br_, bgv_, bb_;
    if (usebg) {
      int byy = min(cy, HB_-1), bxx = min(cx, WB_-1);
      size_t bo = (size_t)byy * WB_ + bxx;
      br_  = bgb[bo];
      bgv_ = bgb[bo + (size_t)HB_*WB_];
      bb_  = bgb[bo + 2*(size_t)HB_*WB_];
    } else { br_ = colr; bgv_ = colg; bb_ = colb; }
    float w1m = 1.f - mval;
    float ir = 0.f, ig = 0.f, ib = 0.f;
    if (mval != 0.f) {
      size_t io = (size_t)oy * W_ + ox;
      ir = imgb[io] * mval;
      ig = imgb[io + HW_] * mval;
      ib = imgb[io + 2*HW_] * mval;
    }
    o[0] = ir + br_  * w1m;
    o[1] = ig + bgv_ * w1m;
    o[2] = ib + bb_  * w1m;
  };
  comp(y0, x0, a00); comp(y0, x1, a01); comp(y1, x0, a10); comp(y1, x1, a11);

  float brf = bri[b];
  float xr[3];
  #pragma unroll
  for (int ch = 0; ch < 3; ++ch) {
    float top = a00[ch] * (1.f - wx) + a01[ch] * wx;
    float bot = a10[ch] * (1.f - wx) + a11[ch] * wx;
    float o = top * (1.f - wy) + bot * wy;
    xr[ch] = clip01(o * brf);
    xout[((size_t)(b*3+ch)*OUT_ + py)*OUT_ + px] = xr[ch];
  }
  float gray = 0.299f*xr[0] + 0.587f*xr[1] + 0.114f*xr[2];

  __shared__ float ssum[256];
  ssum[tid] = gray;
  __syncthreads();
  for (int off = 128; off > 0; off >>= 1) {
    if (tid < off) ssum[tid] += ssum[tid+off];
    __syncthreads();
  }
  if (tid == 0) partial[blk] = ssum[0];
}

// ---------------- reduce gray partials -> mean ----------------
__global__ void k_gmean(const float* __restrict__ partial, float* __restrict__ gmean) {
  int b = blockIdx.x, tid = threadIdx.x;
  __shared__ float s[256];
  s[tid] = partial[b*256 + tid];
  __syncthreads();
  for (int off = 128; off > 0; off >>= 1) {
    if (tid < off) s[tid] += s[tid+off];
    __syncthreads();
  }
  if (tid == 0) gmean[b] = s[0] * (1.f/(float)OO_);
}

// ---------------- contrast + saturation + hue (in-place on d_out x region) ----------------
__global__ void k_color(float* __restrict__ xio, const float* __restrict__ gmean,
                        const float* __restrict__ con, const float* __restrict__ sat,
                        const float* __restrict__ hue) {
  int tid = threadIdx.x;
  int blk = blockIdx.x;
  int b = blk >> 8;
  int p = ((blk & 255) << 8) | tid;
  size_t base = (size_t)b*3*OO_ + p;
  float r  = xio[base];
  float g  = xio[base + OO_];
  float bl = xio[base + 2*OO_];

  float mean = gmean[b];
  float cf = con[b];
  r  = clip01(cf*r  + (1.f-cf)*mean);
  g  = clip01(cf*g  + (1.f-cf)*mean);
  bl = clip01(cf*bl + (1.f-cf)*mean);

  float sf = sat[b];
  float gr = 0.299f*r + 0.587f*g + 0.114f*bl;
  r  = clip01(sf*r  + (1.f-sf)*gr);
  g  = clip01(sf*g  + (1.f-sf)*gr);
  bl = clip01(sf*bl + (1.f-sf)*gr);

  // rgb -> hsv
  const float eps = 1e-8f;
  float mx = fmaxf(r, fmaxf(g, bl));
  float mn = fminf(r, fminf(g, bl));
  float d = mx - mn;
  float inv = 1.f / (d + eps);
  float h;
  if (mx == r)      h = pmodf_((g - bl) * inv, 6.f);
  else if (mx == g) h = (bl - r) * inv + 2.f;
  else              h = (r - g) * inv + 4.f;
  h *= (1.f/6.f);
  if (d <= eps) h = 0.f;
  float s = d / (mx + eps);
  float v = mx;

  h = pmodf_(h + hue[b], 1.f);

  // hsv -> rgb
  float h6 = pmodf_(h, 1.f) * 6.f;
  float fi = floorf(h6);
  float f = h6 - fi;
  int i = ((int)fi) % 6;
  float pp = v * (1.f - s);
  float q  = v * (1.f - f*s);
  float t  = v * (1.f - (1.f - f)*s);
  float rr, gg, bb;
  switch (i) {
    case 0:  rr=v;  gg=t;  bb=pp; break;
    case 1:  rr=q;  gg=v;  bb=pp; break;
    case 2:  rr=pp; gg=v;  bb=t;  break;
    case 3:  rr=pp; gg=q;  bb=v;  break;
    case 4:  rr=t;  gg=pp; bb=v;  break;
    default: rr=v;  gg=pp; bb=q;  break;
  }
  xio[base]         = clip01(rr);
  xio[base + OO_]   = clip01(gg);
  xio[base + 2*OO_] = clip01(bb);
}

// ---------------- bm affine remap ----------------
__global__ void k_bm(const float* __restrict__ bm, const int* __restrict__ bbox,
                     const int* __restrict__ cbuf, float* __restrict__ outp) {
  const size_t N4 = (size_t)B_*2*HW_/4;
  for (size_t i = (size_t)blockIdx.x*blockDim.x + threadIdx.x; i < N4;
       i += (size_t)gridDim.x*blockDim.x) {
    size_t e = i * 4;
    int b  = (int)(e / (2*HW_));
    int ch = (int)((e / HW_) & 1);
    int minx = bbox[b*4+0], maxx = bbox[b*4+1], miny = bbox[b*4+2], maxy = bbox[b*4+3];
    if (maxy < 0) { miny = 0; maxy = H_-1; }
    if (maxx < 0) { minx = 0; maxx = W_-1; }
    int c0 = cbuf[b*5+0], c1 = cbuf[b*5+1], c2 = cbuf[b*5+2], c3 = cbuf[b*5+3];
    float off, sz;
    if (ch == 0) { off = (float)(minx - c0); sz = (float)(maxx - minx + 1 + c0 + c1); }
    else         { off = (float)(miny - c2); sz = (float)(maxy - miny + 1 + c2 + c3); }
    float4 v = ((const float4*)bm)[i];
    float4 o;
    o.x = (v.x - off) / sz * 2.f - 1.f;
    o.y = (v.y - off) / sz * 2.f - 1.f;
    o.z = (v.z - off) / sz * 2.f - 1.f;
    o.w = (v.w - off) / sz * 2.f - 1.f;
    ((float4*)outp)[i] = o;
  }
}

extern "C" void kernel_launch(void* const* d_in, const int* in_sizes, int n_in,
                              void* d_out, int out_size, void* d_ws, size_t ws_size,
                              hipStream_t stream) {
  const float* img = (const float*)d_in[0];
  const float* wc  = (const float*)d_in[1];
  const float* bm  = (const float*)d_in[2];
  const float* bg  = (const float*)d_in[3];
  const float* col = (const float*)d_in[4];
  const float* bri = (const float*)d_in[5];
  const float* con = (const float*)d_in[6];
  const float* sat = (const float*)d_in[7];
  const float* hue = (const float*)d_in[8];
  const int*   cb  = (const int*)d_in[9];

  float* outx  = (float*)d_out;
  float* outbm = outx + (size_t)B_*3*OO_;

  char* ws = (char*)d_ws;
  int*   bbox    = (int*)ws;                      // [0,1024)
  float* gmean   = (float*)(ws + 1024);           // [1024,1280)
  float* partial = (float*)(ws + 4096);           // [4096,69632)
  unsigned char* maskb = (unsigned char*)(ws + 69632);
  int useMask = (ws_size >= (size_t)69632 + (size_t)B_*HW_) ? 1 : 0;

  k_init   <<<1,       64,  0, stream>>>(bbox);
  k_bbox   <<<B_*64,   256, 0, stream>>>(wc, maskb, bbox, useMask);
  k_compose<<<B_*256,  256, 0, stream>>>(img, bg, wc, maskb, col, bri, cb, bbox,
                                         outx, partial, useMask);
  k_gmean  <<<B_,      256, 0, stream>>>(partial, gmean);
  k_color  <<<B_*256,  256, 0, stream>>>(outx, gmean, con, sat, hue);
  k_bm     <<<2048,    256, 0, stream>>>(bm, bbox, cb, outbm);
}

// Round 3
// 188.060 us; speedup vs baseline: 1.1585x; 1.1585x over previous
//
#include <hip/hip_runtime.h>
#include <hip/hip_fp16.h>

#define B_    64
#define H_    448
#define W_    448
#define OUT_  256
#define HB_   486
#define WB_   486
#define HW_   (H_*W_)        // 200704
#define OO_   (OUT_*OUT_)    // 65536
#define F4PP  (HW_/4)        // 50176 float4 per channel plane
#define F4PB  (F4PP/16)      // 3136 float4 per K1 block per plane

__device__ __forceinline__ float clip01(float v) { return fminf(fmaxf(v, 0.f), 1.f); }
__device__ __forceinline__ float pmodf_(float a, float m) {
  float r = fmodf(a, m);
  return (r < 0.f) ? r + m : r;
}

// ---------------- K1: mask (uchar4) + bbox block partials ----------------
__global__ void k1_bboxmask(const float* __restrict__ wc, unsigned char* __restrict__ maskb,
                            int* __restrict__ pb, int useMask) {
  int blk = blockIdx.x, tid = threadIdx.x;
  int s = blk >> 4, slot = blk & 15;
  const float4* w0 = (const float4*)(wc + (size_t)s*3*HW_);
  const float4* w1 = w0 + F4PP;
  const float4* w2 = w1 + F4PP;
  uchar4* mb4 = (uchar4*)(maskb + (size_t)s*HW_);
  int mnX = W_, mxX = -1, mnY = H_, mxY = -1;
  for (int j = tid; j < F4PB; j += 256) {
    int i = slot*F4PB + j;
    float4 a = w0[i], b = w1[i], c = w2[i];
    int m0 = (a.x != 0.f && b.x != 0.f && c.x != 0.f);
    int m1 = (a.y != 0.f && b.y != 0.f && c.y != 0.f);
    int m2 = (a.z != 0.f && b.z != 0.f && c.z != 0.f);
    int m3 = (a.w != 0.f && b.w != 0.f && c.w != 0.f);
    if (useMask)
      mb4[i] = make_uchar4((unsigned char)m0, (unsigned char)m1,
                           (unsigned char)m2, (unsigned char)m3);
    if (m0 | m1 | m2 | m3) {
      int y  = i / 112;          // 112 float4 per 448-px row
      int x0 = (i - y*112) * 4;
      mnY = min(mnY, y); mxY = max(mxY, y);
      int first = m0 ? 0 : (m1 ? 1 : (m2 ? 2 : 3));
      int last  = m3 ? 3 : (m2 ? 2 : (m1 ? 1 : 0));
      mnX = min(mnX, x0 + first);
      mxX = max(mxX, x0 + last);
    }
  }
  __shared__ int sr[4][256];
  sr[0][tid]=mnX; sr[1][tid]=mxX; sr[2][tid]=mnY; sr[3][tid]=mxY;
  __syncthreads();
  for (int off = 128; off > 0; off >>= 1) {
    if (tid < off) {
      sr[0][tid] = min(sr[0][tid], sr[0][tid+off]);
      sr[1][tid] = max(sr[1][tid], sr[1][tid+off]);
      sr[2][tid] = min(sr[2][tid], sr[2][tid+off]);
      sr[3][tid] = max(sr[3][tid], sr[3][tid+off]);
    }
    __syncthreads();
  }
  if (tid == 0) {
    pb[blk*4+0] = sr[0][0]; pb[blk*4+1] = sr[1][0];
    pb[blk*4+2] = sr[2][0]; pb[blk*4+3] = sr[3][0];
  }
}

// ---------------- K0: per-sample params ----------------
__global__ void k0_params(const int* __restrict__ pb, const int* __restrict__ cbuf,
                          int* __restrict__ pint, float* __restrict__ pflt) {
  int b = threadIdx.x;
  if (b >= B_) return;
  int mnX = W_, mxX = -1, mnY = H_, mxY = -1;
  for (int t = 0; t < 16; ++t) {
    int base = (b*16 + t) * 4;
    mnX = min(mnX, pb[base+0]); mxX = max(mxX, pb[base+1]);
    mnY = min(mnY, pb[base+2]); mxY = max(mxY, pb[base+3]);
  }
  if (mxY < 0) { mnY = 0; mxY = H_-1; }
  if (mxX < 0) { mnX = 0; mxX = W_-1; }
  int c0 = cbuf[b*5+0], c1 = cbuf[b*5+1], c2 = cbuf[b*5+2],
      c3 = cbuf[b*5+3], c4 = cbuf[b*5+4];
  int Hp = mxY - mnY + 1 + c2 + c3;
  int Wp = mxX - mnX + 1 + c0 + c1;
  pint[b*16+0] = mnX; pint[b*16+1] = mnY; pint[b*16+2] = mxX; pint[b*16+3] = mxY;
  pint[b*16+4] = c0;  pint[b*16+5] = c2;  pint[b*16+6] = (c4 > 2);
  pint[b*16+7] = Hp;  pint[b*16+8] = Wp;
  pflt[b*8+0] = (float)Wp / (float)OUT_;
  pflt[b*8+1] = (float)Hp / (float)OUT_;
  pflt[b*8+2] = (float)(mnX - c0);  // offx
  pflt[b*8+3] = (float)Wp;          // szx
  pflt[b*8+4] = (float)(mnY - c2);  // offy
  pflt[b*8+5] = (float)Hp;          // szy
}

struct Params {
  int minx, miny, maxx, maxy, c0, c2, usebg, Hp, Wp;
  float scX, scY, colr, colg, colb, brf;
};

// ---------------- K2: compose + brightness + gray partials ----------------
__global__ void k2_compose(const float* __restrict__ img, const float* __restrict__ bg,
                           const float* __restrict__ wc, const unsigned char* __restrict__ maskb,
                           const float* __restrict__ col, const float* __restrict__ bri,
                           const int* __restrict__ pint, const float* __restrict__ pflt,
                           __half* __restrict__ xh, float* __restrict__ xout,
                           float* __restrict__ gpart, int useMask, int useHalf) {
  int tid = threadIdx.x, blk = blockIdx.x;
  int s = blk >> 8;                 // 256 blocks per sample
  int p = ((blk & 255) << 8) | tid;
  int py = p >> 8, px = p & 255;

  __shared__ Params P;
  if (tid == 0) {
    P.minx = pint[s*16+0]; P.miny = pint[s*16+1];
    P.maxx = pint[s*16+2]; P.maxy = pint[s*16+3];
    P.c0 = pint[s*16+4];   P.c2 = pint[s*16+5];
    P.usebg = pint[s*16+6]; P.Hp = pint[s*16+7]; P.Wp = pint[s*16+8];
    P.scX = pflt[s*8+0]; P.scY = pflt[s*8+1];
    P.colr = col[s*3+0]; P.colg = col[s*3+1]; P.colb = col[s*3+2];
    P.brf = bri[s];
  }
  __syncthreads();

  float sy = fmaxf((py + 0.5f) * P.scY - 0.5f, 0.f);
  int   y0 = (int)sy;
  float wy = sy - (float)y0;
  y0 = min(y0, P.Hp - 1);
  int y1 = min(y0 + 1, P.Hp - 1);

  float sx = fmaxf((px + 0.5f) * P.scX - 0.5f, 0.f);
  int   x0 = (int)sx;
  float wx = sx - (float)x0;
  x0 = min(x0, P.Wp - 1);
  int x1 = min(x0 + 1, P.Wp - 1);

  const float* imgb = img + (size_t)s*3*HW_;
  const float* bgb  = bg  + (size_t)s*3*HB_*WB_;
  const float* w0p  = wc  + (size_t)s*3*HW_;
  const unsigned char* mb = maskb + (size_t)s*HW_;

  float a00[3], a01[3], a10[3], a11[3];
  auto comp = [&](int cy, int cx, float* o) {
    int oy = cy - P.c2 + P.miny;
    int ox = cx - P.c0 + P.minx;
    bool valid = (oy >= P.miny) && (oy <= P.maxy) &&
                 (ox >= P.minx) && (ox <= P.maxx);
    float mval = 0.f;
    if (valid) {
      int mi = oy * W_ + ox;
      if (useMask) mval = (float)mb[mi];
      else mval = (w0p[mi] != 0.f && w0p[mi+HW_] != 0.f && w0p[mi+2*HW_] != 0.f) ? 1.f : 0.f;
    }
    float br_, bgv_, bb_;
    if (P.usebg) {
      int byy = min(cy, HB_-1), bxx = min(cx, WB_-1);
      size_t bo = (size_t)byy * WB_ + bxx;
      br_  = bgb[bo];
      bgv_ = bgb[bo + (size_t)HB_*WB_];
      bb_  = bgb[bo + 2*(size_t)HB_*WB_];
    } else { br_ = P.colr; bgv_ = P.colg; bb_ = P.colb; }
    float w1m = 1.f - mval;
    float ir = 0.f, ig = 0.f, ib = 0.f;
    if (mval != 0.f) {
      size_t io = (size_t)oy * W_ + ox;
      ir = imgb[io]; ig = imgb[io + HW_]; ib = imgb[io + 2*HW_];
    }
    o[0] = ir + br_  * w1m;
    o[1] = ig + bgv_ * w1m;
    o[2] = ib + bb_  * w1m;
  };
  comp(y0, x0, a00); comp(y0, x1, a01); comp(y1, x0, a10); comp(y1, x1, a11);

  float xr[3];
  #pragma unroll
  for (int ch = 0; ch < 3; ++ch) {
    float top = a00[ch] * (1.f - wx) + a01[ch] * wx;
    float bot = a10[ch] * (1.f - wx) + a11[ch] * wx;
    float o = top * (1.f - wy) + bot * wy;
    xr[ch] = clip01(o * P.brf);
    size_t oi = (size_t)(s*3 + ch)*OO_ + p;
    if (useHalf) xh[oi] = __float2half(xr[ch]);
    else         xout[oi] = xr[ch];
  }
  float gray = 0.299f*xr[0] + 0.587f*xr[1] + 0.114f*xr[2];

  __shared__ float sf[256];
  sf[tid] = gray;
  __syncthreads();
  for (int off = 128; off > 0; off >>= 1) {
    if (tid < off) sf[tid] += sf[tid+off];
    __syncthreads();
  }
  if (tid == 0) gpart[blk] = sf[0];
}

// ---------------- Kg: gray mean ----------------
__global__ void kg_gmean(const float* __restrict__ gpart, float* __restrict__ gmean) {
  int b = blockIdx.x, tid = threadIdx.x;
  __shared__ float sf[256];
  sf[tid] = gpart[b*256 + tid];
  __syncthreads();
  for (int off = 128; off > 0; off >>= 1) {
    if (tid < off) sf[tid] += sf[tid+off];
    __syncthreads();
  }
  if (tid == 0) gmean[b] = sf[0] * (1.f/(float)OO_);
}

// ---------------- K3: contrast/saturation/hue, 2 px per thread ----------------
__global__ void k3_color(const __half2* __restrict__ xh2, const float* __restrict__ gmean,
                         const float* __restrict__ con, const float* __restrict__ sat,
                         const float* __restrict__ hue, float* __restrict__ xout,
                         int useHalf) {
  int tid = threadIdx.x, blk = blockIdx.x;
  int s = blk >> 7;                    // 128 blocks per sample
  int p = ((blk & 127) << 8) | tid;    // 2-px unit within plane [0, 32768)
  const int PL = OO_/2;                // 32768
  size_t base = (size_t)s*3*PL + p;
  float2* xo2 = (float2*)xout;

  float2 rc, gc, bc;
  if (useHalf) {
    rc = __half22float2(xh2[base]);
    gc = __half22float2(xh2[base + PL]);
    bc = __half22float2(xh2[base + 2*PL]);
  } else {
    rc = xo2[base]; gc = xo2[base + PL]; bc = xo2[base + 2*PL];
  }

  float mean = gmean[s];
  float cf = con[s], sfc = sat[s], hu = hue[s];

  float rin[2] = {rc.x, rc.y}, gin[2] = {gc.x, gc.y}, bin[2] = {bc.x, bc.y};
  float rot[2], got[2], bot_[2];
  #pragma unroll
  for (int l = 0; l < 2; ++l) {
    float r = rin[l], g = gin[l], bl = bin[l];
    r  = clip01(cf*r  + (1.f-cf)*mean);
    g  = clip01(cf*g  + (1.f-cf)*mean);
    bl = clip01(cf*bl + (1.f-cf)*mean);

    float gr = 0.299f*r + 0.587f*g + 0.114f*bl;
    r  = clip01(sfc*r  + (1.f-sfc)*gr);
    g  = clip01(sfc*g  + (1.f-sfc)*gr);
    bl = clip01(sfc*bl + (1.f-sfc)*gr);

    const float eps = 1e-8f;
    float mx = fmaxf(r, fmaxf(g, bl));
    float mn = fminf(r, fminf(g, bl));
    float d  = mx - mn;
    float inv = 1.f / (d + eps);
    float h;
    if (mx == r)      h = pmodf_((g - bl) * inv, 6.f);
    else if (mx == g) h = (bl - r) * inv + 2.f;
    else              h = (r - g) * inv + 4.f;
    h *= (1.f/6.f);
    if (d <= eps) h = 0.f;
    float sv = d / (mx + eps);
    float v  = mx;

    h = pmodf_(h + hu, 1.f);

    float h6 = pmodf_(h, 1.f) * 6.f;
    float fi = floorf(h6);
    float f  = h6 - fi;
    int   i6 = ((int)fi) % 6;
    float pp = v * (1.f - sv);
    float q  = v * (1.f - f*sv);
    float t  = v * (1.f - (1.f - f)*sv);
    float rr, gg, bb;
    switch (i6) {
      case 0:  rr=v;  gg=t;  bb=pp; break;
      case 1:  rr=q;  gg=v;  bb=pp; break;
      case 2:  rr=pp; gg=v;  bb=t;  break;
      case 3:  rr=pp; gg=q;  bb=v;  break;
      case 4:  rr=t;  gg=pp; bb=v;  break;
      default: rr=v;  gg=pp; bb=q;  break;
    }
    rot[l] = clip01(rr); got[l] = clip01(gg); bot_[l] = clip01(bb);
  }
  xo2[base]        = make_float2(rot[0], rot[1]);
  xo2[base + PL]   = make_float2(got[0], got[1]);
  xo2[base + 2*PL] = make_float2(bot_[0], bot_[1]);
}

// ---------------- K4: bm affine remap ----------------
__global__ void k4_bm(const float* __restrict__ bm, const float* __restrict__ pflt,
                      float* __restrict__ outp) {
  const size_t N4 = (size_t)B_*2*HW_/4;   // 6422528 float4
  for (size_t i = (size_t)blockIdx.x*blockDim.x + threadIdx.x; i < N4;
       i += (size_t)gridDim.x*blockDim.x) {
    int b  = (int)(i / (2*F4PP));
    int ch = (int)((i / F4PP) & 1);
    float off_ = pflt[b*8 + 2 + 2*ch];
    float sz_  = pflt[b*8 + 3 + 2*ch];
    float inv = 2.f / sz_;
    float4 v = ((const float4*)bm)[i];
    float4 o;
    o.x = (v.x - off_) * inv - 1.f;
    o.y = (v.y - off_) * inv - 1.f;
    o.z = (v.z - off_) * inv - 1.f;
    o.w = (v.w - off_) * inv - 1.f;
    ((float4*)outp)[i] = o;
  }
}

extern "C" void kernel_launch(void* const* d_in, const int* in_sizes, int n_in,
                              void* d_out, int out_size, void* d_ws, size_t ws_size,
                              hipStream_t stream) {
  const float* img = (const float*)d_in[0];
  const float* wc  = (const float*)d_in[1];
  const float* bm  = (const float*)d_in[2];
  const float* bg  = (const float*)d_in[3];
  const float* col = (const float*)d_in[4];
  const float* bri = (const float*)d_in[5];
  const float* con = (const float*)d_in[6];
  const float* sat = (const float*)d_in[7];
  const float* hue = (const float*)d_in[8];
  const int*   cb  = (const int*)d_in[9];

  float* outx  = (float*)d_out;
  float* outbm = outx + (size_t)B_*3*OO_;

  char* ws = (char*)d_ws;
  int*   pb    = (int*)ws;                     // [0, 16384)
  int*   pint  = (int*)(ws + 16384);           // [16384, 20480)
  float* pflt  = (float*)(ws + 20480);         // [20480, 22528)
  float* gmean = (float*)(ws + 24576);         // [24576, 24832)
  float* gpart = (float*)(ws + 28672);         // [28672, 94208)
  unsigned char* maskb = (unsigned char*)(ws + 94208);      // 12,845,056 B
  __half* xh = (__half*)(ws + 12939264);       // 25,165,824 B -> ends 38,105,088

  int useMask = (ws_size >= (size_t)12939264) ? 1 : 0;
  int useHalf = (ws_size >= (size_t)38105088) ? 1 : 0;

  k1_bboxmask<<<1024,  256, 0, stream>>>(wc, maskb, pb, useMask);
  k0_params  <<<1,     64,  0, stream>>>(pb, cb, pint, pflt);
  k2_compose <<<16384, 256, 0, stream>>>(img, bg, wc, maskb, col, bri, pint, pflt,
                                         xh, outx, gpart, useMask, useHalf);
  kg_gmean   <<<64,    256, 0, stream>>>(gpart, gmean);
  k4_bm      <<<2048,  256, 0, stream>>>(bm, pflt, outbm);
  k3_color   <<<8192,  256, 0, stream>>>((const __half2*)xh, gmean, con, sat, hue,
                                         outx, useHalf);
}